// Round 6
// baseline (1074.623 us; speedup 1.0000x reference)
//
#include <hip/hip_runtime.h>
#include <hip/hip_bf16.h>

typedef unsigned short u16;
typedef __bf16 bf16x8 __attribute__((ext_vector_type(8)));
typedef float f32x4 __attribute__((ext_vector_type(4)));

__device__ __forceinline__ u16 f2b(float f) {
  __hip_bfloat16 h = __float2bfloat16(f);
  return *reinterpret_cast<u16*>(&h);
}
__device__ __forceinline__ float b2f(u16 v) {
  unsigned int u = ((unsigned int)v) << 16;
  union { unsigned int u; float f; } c; c.u = u; return c.f;
}
// tanh-approx GELU via exp2: max |err| ~3e-4
__device__ __forceinline__ float gelu_f(float x) {
  float t = x * x;
  float u = x * fmaf(t, -0.10294576f, -2.30220813f);
  float e = exp2f(u);
  return x * __builtin_amdgcn_rcpf(1.0f + e);
}

// ---------------- weight f32 -> bf16 ----------------
__global__ __launch_bounds__(256) void k_cvt(const float* __restrict__ s, u16* __restrict__ d, int n) {
  int i = blockIdx.x * 256 + threadIdx.x;
  if (i < n) d[i] = f2b(s[i]);
}

// ---------------- patchify + pos-embed + LN1 fused ----------------
__global__ __launch_bounds__(256) void k_patchify_ln(const float* __restrict__ x,
                                                     const float* __restrict__ rowe,
                                                     const float* __restrict__ cole,
                                                     const float* __restrict__ g,
                                                     const float* __restrict__ bta,
                                                     u16* __restrict__ resid,
                                                     u16* __restrict__ xn, int b0) {
  __shared__ float tile[192 * 133];
  __shared__ float ps[256], pq[256], mb[128], rb[128];
  const int h = blockIdx.x, bb = blockIdx.y, b = b0 + bb;
  const int tid = threadIdx.x;
  const int p1 = h & 7, hy = h >> 3;
  const float* xs = x + ((size_t)b * 192 * 128 + (size_t)h) * 128;
  for (int i = 0; i < 24; i++) {
    int idx = i * 256 + tid;
    int c = idx >> 5, w4 = idx & 31;
    const float4 v = *reinterpret_cast<const float4*>(xs + (size_t)c * 16384 + w4 * 4);
    float a0, a1, a2, a3;
    if (c < 96) {
      float pv = rowe[p1 * 96 + c];
      a0 = a1 = a2 = a3 = pv;
    } else {
      int w = w4 * 4;
      a0 = cole[((w)     & 7) * 96 + c - 96];
      a1 = cole[((w + 1) & 7) * 96 + c - 96];
      a2 = cole[((w + 2) & 7) * 96 + c - 96];
      a3 = cole[((w + 3) & 7) * 96 + c - 96];
    }
    float* t = &tile[c * 133 + w4 * 4];
    t[0] = v.x + a0; t[1] = v.y + a1; t[2] = v.z + a2; t[3] = v.w + a3;
  }
  __syncthreads();
  {
    int w = tid & 127, half = tid >> 7;
    float s = 0.f, q = 0.f;
    for (int c = half * 96; c < half * 96 + 96; c++) {
      float v = tile[c * 133 + w];
      s += v; q += v * v;
    }
    ps[tid] = s; pq[tid] = q;
  }
  __syncthreads();
  if (tid < 128) {
    float s = ps[tid] + ps[tid + 128];
    float q = pq[tid] + pq[tid + 128];
    float mean = s * (1.f / 192.f);
    float var = q * (1.f / 192.f) - mean * mean;
    mb[tid] = mean;
    rb[tid] = rsqrtf(var + 1e-5f);
  }
  __syncthreads();
  for (int i = 0; i < 96; i++) {
    int idx = i * 256 + tid;
    int w = idx / 192, c = idx - w * 192;
    float v = tile[c * 133 + w];
    int wx = w >> 3, p2 = w & 7;
    size_t rr = ((size_t)((bb * 16 + hy) * 16 + wx)) * 64 + p1 * 8 + p2;
    resid[rr * 192 + c] = f2b(v);
    xn[rr * 192 + c] = f2b((v - mb[w]) * rb[w] * g[c] + bta[c]);
  }
}

// ---------------- LayerNorm (wave per token) f32 -> bf16 (LN2) ----------------
__global__ __launch_bounds__(256) void k_ln(const float* __restrict__ xin,
                                            const float* __restrict__ g,
                                            const float* __restrict__ bta,
                                            u16* __restrict__ outp) {
  const int wid = threadIdx.x >> 6, lane = threadIdx.x & 63;
  const size_t row = (size_t)blockIdx.x * 4 + wid;
  const float* p = xin + row * 192;
  float v0 = p[lane], v1 = p[lane + 64], v2 = p[lane + 128];
  float s = v0 + v1 + v2, q = v0 * v0 + v1 * v1 + v2 * v2;
  for (int m = 32; m >= 1; m >>= 1) { s += __shfl_xor(s, m, 64); q += __shfl_xor(q, m, 64); }
  float mean = s * (1.0f / 192.0f);
  float var = q * (1.0f / 192.0f) - mean * mean;
  float rstd = rsqrtf(var + 1e-5f);
  u16* o = outp + row * 192;
  o[lane]       = f2b((v0 - mean) * rstd * g[lane]       + bta[lane]);
  o[lane + 64]  = f2b((v1 - mean) * rstd * g[lane + 64]  + bta[lane + 64]);
  o[lane + 128] = f2b((v2 - mean) * rstd * g[lane + 128] + bta[lane + 128]);
}

// ---------------- no-LDS direct-load GEMM: out = A(M,K) @ W(N,K)^T + bias ----------------
// Block 256 = 4 waves (2M x 2N) over a 64 x BN tile. No LDS, no barriers:
// A/B fragments loaded straight to VGPR (B is L2-resident weights; A-frag =
// 16 rows x 64B segments). Compiler pipelines freely; TLP from ~0-LDS occupancy.
enum { EP_BF16 = 0, EP_GELU_BF16 = 1, EP_RESID_F32 = 2, EP_GELU_ADD_F32 = 3 };

template <int BN, int EP, int KTOT>
__global__ __launch_bounds__(256) void k_gemmd(const u16* __restrict__ A,
                                               const u16* __restrict__ W,
                                               const float* __restrict__ bias,
                                               const void* __restrict__ aux,
                                               void* __restrict__ outp, int Nout) {
  constexpr int NF = BN / 32;  // n-frags per wave (wave covers BN/2 cols)
  const int tid = threadIdx.x;
  const int lane = tid & 63, wid = tid >> 6;
  const int lo = lane & 15, hi = lane >> 4;
  const int wm = wid >> 1, wn = wid & 1;
  const int m0 = blockIdx.y * 64 + wm * 32;
  const int n0 = blockIdx.x * BN + wn * (BN / 2);
  const u16* pa0 = A + (size_t)(m0 + lo) * KTOT + hi * 8;
  const u16* pa1 = pa0 + (size_t)16 * KTOT;
  const u16* pb[NF];
#pragma unroll
  for (int nj = 0; nj < NF; nj++)
    pb[nj] = W + (size_t)(n0 + nj * 16 + lo) * KTOT + hi * 8;

  f32x4 acc[2][NF] = {};
#pragma unroll 6
  for (int kt = 0; kt < KTOT / 32; kt++) {
    bf16x8 a0 = *reinterpret_cast<const bf16x8*>(pa0 + kt * 32);
    bf16x8 a1 = *reinterpret_cast<const bf16x8*>(pa1 + kt * 32);
    bf16x8 b[NF];
#pragma unroll
    for (int nj = 0; nj < NF; nj++)
      b[nj] = *reinterpret_cast<const bf16x8*>(pb[nj] + kt * 32);
#pragma unroll
    for (int nj = 0; nj < NF; nj++) {
      acc[0][nj] = __builtin_amdgcn_mfma_f32_16x16x32_bf16(a0, b[nj], acc[0][nj], 0, 0, 0);
      acc[1][nj] = __builtin_amdgcn_mfma_f32_16x16x32_bf16(a1, b[nj], acc[1][nj], 0, 0, 0);
    }
  }
  // epilogue: D frag col = lane&15, row = (lane>>4)*4 + r
#pragma unroll
  for (int mi = 0; mi < 2; mi++)
#pragma unroll
    for (int nj = 0; nj < NF; nj++) {
      int gn = n0 + nj * 16 + lo;
      float bv = bias[gn];
#pragma unroll
      for (int r = 0; r < 4; r++) {
        int gm = m0 + mi * 16 + hi * 4 + r;
        size_t oidx = (size_t)gm * Nout + gn;
        float v = acc[mi][nj][r] + bv;
        if (EP == EP_BF16)           ((u16*)outp)[oidx] = f2b(v);
        else if (EP == EP_GELU_BF16) ((u16*)outp)[oidx] = f2b(gelu_f(v));
        else if (EP == EP_RESID_F32) ((float*)outp)[oidx] = v + b2f(((const u16*)aux)[oidx]);
        else                         ((float*)outp)[oidx] = gelu_f(v) + ((const float*)aux)[oidx];
      }
    }
}

// ---------------- windowed attention: block = 1 window, 6 waves = 6 heads ----------------
__global__ __launch_bounds__(384) void k_attn(const u16* __restrict__ qkv, u16* __restrict__ o) {
  __shared__ __align__(16) u16 qk_lds[64 * 392];
  __shared__ __align__(16) u16 vt[192 * 72];
  __shared__ __align__(16) u16 pbuf[6 * 64 * 72];
  const int tid = threadIdx.x;
  const u16* src = qkv + (size_t)blockIdx.x * 64 * 576;
  for (int i = 0; i < 8; i++) {
    int gq = i * 384 + tid, row = gq / 48, kk = gq % 48;
    uint4 d = *reinterpret_cast<const uint4*>(src + row * 576 + kk * 8);
    *reinterpret_cast<uint4*>(&qk_lds[row * 392 + kk * 8]) = d;
  }
  for (int i = 0; i < 4; i++) {
    int gq = i * 384 + tid, row = gq / 24, kk = gq % 24;
    uint4 d = *reinterpret_cast<const uint4*>(src + row * 576 + 384 + kk * 8);
    const u16* ds = reinterpret_cast<const u16*>(&d);
#pragma unroll
    for (int e = 0; e < 8; e++) vt[(kk * 8 + e) * 72 + row] = ds[e];
  }
  __syncthreads();
  const int wid = tid >> 6, lane = tid & 63, lo = lane & 15, hi = lane >> 4;
  f32x4 s[4][4] = {};
  const u16* pq = &qk_lds[lo * 392 + wid * 32 + hi * 8];
  const u16* pk = &qk_lds[lo * 392 + 192 + wid * 32 + hi * 8];
  bf16x8 qa[4], kb[4];
#pragma unroll
  for (int mi = 0; mi < 4; mi++) qa[mi] = *reinterpret_cast<const bf16x8*>(pq + mi * 16 * 392);
#pragma unroll
  for (int nj = 0; nj < 4; nj++) kb[nj] = *reinterpret_cast<const bf16x8*>(pk + nj * 16 * 392);
#pragma unroll
  for (int mi = 0; mi < 4; mi++)
#pragma unroll
    for (int nj = 0; nj < 4; nj++)
      s[mi][nj] = __builtin_amdgcn_mfma_f32_16x16x32_bf16(qa[mi], kb[nj], s[mi][nj], 0, 0, 0);
  const float scale = 0.1767766952966369f;
#pragma unroll
  for (int mi = 0; mi < 4; mi++)
#pragma unroll
    for (int nj = 0; nj < 4; nj++)
#pragma unroll
      for (int r = 0; r < 4; r++) s[mi][nj][r] *= scale;
#pragma unroll
  for (int mi = 0; mi < 4; mi++)
#pragma unroll
    for (int r = 0; r < 4; r++) {
      float mx = fmaxf(fmaxf(s[mi][0][r], s[mi][1][r]), fmaxf(s[mi][2][r], s[mi][3][r]));
      mx = fmaxf(mx, __shfl_xor(mx, 1, 64));
      mx = fmaxf(mx, __shfl_xor(mx, 2, 64));
      mx = fmaxf(mx, __shfl_xor(mx, 4, 64));
      mx = fmaxf(mx, __shfl_xor(mx, 8, 64));
      float e0 = __expf(s[mi][0][r] - mx), e1 = __expf(s[mi][1][r] - mx);
      float e2 = __expf(s[mi][2][r] - mx), e3 = __expf(s[mi][3][r] - mx);
      float sm = e0 + e1 + e2 + e3;
      sm += __shfl_xor(sm, 1, 64);
      sm += __shfl_xor(sm, 2, 64);
      sm += __shfl_xor(sm, 4, 64);
      sm += __shfl_xor(sm, 8, 64);
      float inv = 1.0f / sm;
      int i = mi * 16 + hi * 4 + r;
      u16* pr = &pbuf[wid * 4608 + i * 72 + lo];
      pr[0]  = f2b(e0 * inv);
      pr[16] = f2b(e1 * inv);
      pr[32] = f2b(e2 * inv);
      pr[48] = f2b(e3 * inv);
    }
  f32x4 oacc[4][2] = {};
  const u16* pp = &pbuf[wid * 4608 + lo * 72 + hi * 8];
  const u16* pv = &vt[(wid * 32 + lo) * 72 + hi * 8];
#pragma unroll
  for (int kt = 0; kt < 2; kt++) {
    bf16x8 pa[4], vb[2];
#pragma unroll
    for (int mi = 0; mi < 4; mi++) pa[mi] = *reinterpret_cast<const bf16x8*>(pp + mi * 16 * 72 + kt * 32);
#pragma unroll
    for (int ni = 0; ni < 2; ni++) vb[ni] = *reinterpret_cast<const bf16x8*>(pv + ni * 16 * 72 + kt * 32);
#pragma unroll
    for (int mi = 0; mi < 4; mi++)
#pragma unroll
      for (int ni = 0; ni < 2; ni++)
        oacc[mi][ni] = __builtin_amdgcn_mfma_f32_16x16x32_bf16(pa[mi], vb[ni], oacc[mi][ni], 0, 0, 0);
  }
#pragma unroll
  for (int mi = 0; mi < 4; mi++)
#pragma unroll
    for (int ni = 0; ni < 2; ni++)
#pragma unroll
      for (int r = 0; r < 4; r++) {
        int i = mi * 16 + hi * 4 + r, d = ni * 16 + lo;
        o[((size_t)blockIdx.x * 64 + i) * 192 + wid * 32 + d] = f2b(oacc[mi][ni][r]);
      }
}

// ---------------- un-patchify ----------------
__global__ __launch_bounds__(256) void k_unpatch(const float* __restrict__ xf, float* __restrict__ outp, int b0) {
  __shared__ float tile[128 * 65];
  const int cc = blockIdx.x, h = blockIdx.y, bb = blockIdx.z, b = b0 + bb;
  const int tid = threadIdx.x;
  const int p1 = h & 7, hy = h >> 3;
  for (int i = 0; i < 32; i++) {
    int idx = i * 256 + tid, t = idx >> 6, c = idx & 63;
    int wx = t >> 3, p2 = t & 7;
    int rr = ((bb * 16 + hy) * 16 + wx) * 64 + p1 * 8 + p2;
    tile[t * 65 + c] = xf[(size_t)rr * 192 + cc * 64 + c];
  }
  __syncthreads();
  for (int i = 0; i < 32; i++) {
    int idx = i * 256 + tid, c = idx >> 7, w = idx & 127;
    outp[((size_t)(b * 192 + cc * 64 + c) * 128 + h) * 128 + w] = tile[w * 65 + c];
  }
}

extern "C" void kernel_launch(void* const* d_in, const int* in_sizes, int n_in,
                              void* d_out, int out_size, void* d_ws, size_t ws_size,
                              hipStream_t stream) {
  const float* x    = (const float*)d_in[0];
  const float* rowe = (const float*)d_in[1];
  const float* cole = (const float*)d_in[2];
  const float* ln1g = (const float*)d_in[3];
  const float* ln1b = (const float*)d_in[4];
  const float* ipw  = (const float*)d_in[5];
  const float* ipb  = (const float*)d_in[6];
  const float* outw = (const float*)d_in[7];
  const float* outb = (const float*)d_in[8];
  const float* ln2g = (const float*)d_in[9];
  const float* ln2b = (const float*)d_in[10];
  const float* w1   = (const float*)d_in[11];
  const float* b1   = (const float*)d_in[12];
  const float* w2   = (const float*)d_in[13];
  const float* b2   = (const float*)d_in[14];
  float* outp = (float*)d_out;

  char* p = (char*)d_ws;
  auto alloc = [&](size_t bytes) -> void* {
    void* r = (void*)p;
    p += (bytes + 255) & ~(size_t)255;
    return r;
  };
  u16* wq  = (u16*)alloc(110592 * 2);
  u16* wo  = (u16*)alloc(36864 * 2);
  u16* wf1 = (u16*)alloc(147456 * 2);
  u16* wf2 = (u16*)alloc(147456 * 2);

  size_t used = (size_t)(p - (char*)d_ws);
  size_t avail = (ws_size > used) ? (ws_size - used) : 0;
  // per-token bytes: resid 384 + xn 384 + big 1536 + obuf 384 + xp2 768 + xfin 768 = 4224
  int NC = 1;
  while (NC < 8 && (size_t)(131072 / NC) * 4224 + 8192 > avail) NC *= 2;
  const int Bc = 8 / NC;
  const size_t Mc = (size_t)Bc * 16384;

  u16*   resid = (u16*)alloc(Mc * 192 * 2);
  u16*   xn    = (u16*)alloc(Mc * 192 * 2);
  u16*   big   = (u16*)alloc(Mc * 768 * 2);  // qkv then h1
  u16*   obuf  = (u16*)alloc(Mc * 192 * 2);
  float* xp2   = (float*)alloc(Mc * 192 * 4);
  float* xfin  = (float*)alloc(Mc * 192 * 4);

  k_cvt<<<dim3((110592 + 255) / 256), dim3(256), 0, stream>>>(ipw, wq, 110592);
  k_cvt<<<dim3((36864 + 255) / 256), dim3(256), 0, stream>>>(outw, wo, 36864);
  k_cvt<<<dim3((147456 + 255) / 256), dim3(256), 0, stream>>>(w1, wf1, 147456);
  k_cvt<<<dim3((147456 + 255) / 256), dim3(256), 0, stream>>>(w2, wf2, 147456);

  for (int ch = 0; ch < NC; ch++) {
    int b0 = ch * Bc;
    k_patchify_ln<<<dim3(128, Bc), dim3(256), 0, stream>>>(x, rowe, cole, ln1g, ln1b, resid, xn, b0);
    k_gemmd<96, EP_BF16, 192><<<dim3(6, (unsigned)(Mc / 64)), dim3(256), 0, stream>>>(xn, wq, ipb, nullptr, big, 576);
    k_attn<<<dim3((unsigned)(Bc * 256)), dim3(384), 0, stream>>>(big, obuf);
    k_gemmd<96, EP_RESID_F32, 192><<<dim3(2, (unsigned)(Mc / 64)), dim3(256), 0, stream>>>(obuf, wo, outb, resid, xp2, 192);
    k_ln<<<dim3((unsigned)(Mc / 4)), dim3(256), 0, stream>>>(xp2, ln2g, ln2b, xn);
    k_gemmd<128, EP_GELU_BF16, 192><<<dim3(6, (unsigned)(Mc / 64)), dim3(256), 0, stream>>>(xn, wf1, b1, nullptr, big, 768);
    k_gemmd<96, EP_GELU_ADD_F32, 768><<<dim3(2, (unsigned)(Mc / 64)), dim3(256), 0, stream>>>(big, wf2, b2, xp2, xfin, 192);
    k_unpatch<<<dim3(3, 128, Bc), dim3(256), 0, stream>>>(xfin, outp, b0);
  }
}

// Round 7
// 705.941 us; speedup vs baseline: 1.5223x; 1.5223x over previous
//
#include <hip/hip_runtime.h>
#include <hip/hip_bf16.h>

typedef unsigned short u16;
typedef __bf16 bf16x8 __attribute__((ext_vector_type(8)));
typedef float f32x4 __attribute__((ext_vector_type(4)));

__device__ __forceinline__ u16 f2b(float f) {
  __hip_bfloat16 h = __float2bfloat16(f);
  return *reinterpret_cast<u16*>(&h);
}
__device__ __forceinline__ float b2f(u16 v) {
  unsigned int u = ((unsigned int)v) << 16;
  union { unsigned int u; float f; } c; c.u = u; return c.f;
}
// tanh-approx GELU via exp2: max |err| ~3e-4
__device__ __forceinline__ float gelu_f(float x) {
  float t = x * x;
  float u = x * fmaf(t, -0.10294576f, -2.30220813f);
  float e = exp2f(u);
  return x * __builtin_amdgcn_rcpf(1.0f + e);
}

// ---------------- weight f32 -> bf16 ----------------
__global__ __launch_bounds__(256) void k_cvt(const float* __restrict__ s, u16* __restrict__ d, int n) {
  int i = blockIdx.x * 256 + threadIdx.x;
  if (i < n) d[i] = f2b(s[i]);
}

// ---------------- patchify + pos-embed + LN1 fused ----------------
__global__ __launch_bounds__(256) void k_patchify_ln(const float* __restrict__ x,
                                                     const float* __restrict__ rowe,
                                                     const float* __restrict__ cole,
                                                     const float* __restrict__ g,
                                                     const float* __restrict__ bta,
                                                     u16* __restrict__ resid,
                                                     u16* __restrict__ xn, int b0) {
  __shared__ float tile[192 * 133];
  __shared__ float ps[256], pq[256], mb[128], rb[128];
  const int h = blockIdx.x, bb = blockIdx.y, b = b0 + bb;
  const int tid = threadIdx.x;
  const int p1 = h & 7, hy = h >> 3;
  const float* xs = x + ((size_t)b * 192 * 128 + (size_t)h) * 128;
  for (int i = 0; i < 24; i++) {
    int idx = i * 256 + tid;
    int c = idx >> 5, w4 = idx & 31;
    const float4 v = *reinterpret_cast<const float4*>(xs + (size_t)c * 16384 + w4 * 4);
    float a0, a1, a2, a3;
    if (c < 96) {
      float pv = rowe[p1 * 96 + c];
      a0 = a1 = a2 = a3 = pv;
    } else {
      int w = w4 * 4;
      a0 = cole[((w)     & 7) * 96 + c - 96];
      a1 = cole[((w + 1) & 7) * 96 + c - 96];
      a2 = cole[((w + 2) & 7) * 96 + c - 96];
      a3 = cole[((w + 3) & 7) * 96 + c - 96];
    }
    float* t = &tile[c * 133 + w4 * 4];
    t[0] = v.x + a0; t[1] = v.y + a1; t[2] = v.z + a2; t[3] = v.w + a3;
  }
  __syncthreads();
  {
    int w = tid & 127, half = tid >> 7;
    float s = 0.f, q = 0.f;
    for (int c = half * 96; c < half * 96 + 96; c++) {
      float v = tile[c * 133 + w];
      s += v; q += v * v;
    }
    ps[tid] = s; pq[tid] = q;
  }
  __syncthreads();
  if (tid < 128) {
    float s = ps[tid] + ps[tid + 128];
    float q = pq[tid] + pq[tid + 128];
    float mean = s * (1.f / 192.f);
    float var = q * (1.f / 192.f) - mean * mean;
    mb[tid] = mean;
    rb[tid] = rsqrtf(var + 1e-5f);
  }
  __syncthreads();
  for (int i = 0; i < 96; i++) {
    int idx = i * 256 + tid;
    int w = idx / 192, c = idx - w * 192;
    float v = tile[c * 133 + w];
    int wx = w >> 3, p2 = w & 7;
    size_t rr = ((size_t)((bb * 16 + hy) * 16 + wx)) * 64 + p1 * 8 + p2;
    resid[rr * 192 + c] = f2b(v);
    xn[rr * 192 + c] = f2b((v - mb[w]) * rb[w] * g[c] + bta[c]);
  }
}

// ---------------- 2-deep pipelined GEMM (R5 structure, proven 61us FFN2) ----------------
enum { EP_BF16 = 0, EP_GELU_BF16 = 1, EP_GELU_ADD = 3 };

template <int BN, int EP, int KTOT>
__global__ __launch_bounds__(256, 2) void k_gemm3(const u16* __restrict__ A,
                                                  const u16* __restrict__ W,
                                                  const float* __restrict__ bias,
                                                  const void* __restrict__ aux,
                                                  void* __restrict__ outp, int Nout) {
  constexpr int NF = BN / 32;
  constexpr int NBS = BN / 32;
  constexpr int NK = KTOT / 64;
  __shared__ __align__(16) u16 ldsA[2][128 * 64];
  __shared__ __align__(16) u16 ldsB[2][BN * 64];
  const int tid = threadIdx.x;
  const int lane = tid & 63, wid = tid >> 6;
  const int lo = lane & 15, hi = lane >> 4;
  const int wm = wid >> 1, wn = wid & 1;
  const int n0 = blockIdx.x * BN;
  const int m0 = blockIdx.y * 128;

  const int lrow = lane >> 3, lk = (lane & 7) * 8;
  const u16* agp[4];
  const u16* bgp[NBS];
#pragma unroll
  for (int i = 0; i < 4; i++)
    agp[i] = A + (size_t)(m0 + i * 32 + wid * 8 + lrow) * KTOT + lk;
#pragma unroll
  for (int i = 0; i < NBS; i++)
    bgp[i] = W + (size_t)(n0 + i * 32 + wid * 8 + lrow) * KTOT + lk;

  auto stage = [&](int kc, int buf) {
#pragma unroll
    for (int i = 0; i < 4; i++)
      __builtin_amdgcn_global_load_lds(
          (const __attribute__((address_space(1))) void*)(agp[i] + kc * 64),
          (__attribute__((address_space(3))) void*)(&ldsA[buf][(i * 4 + wid) * 512]), 16, 0, 0);
#pragma unroll
    for (int i = 0; i < NBS; i++)
      __builtin_amdgcn_global_load_lds(
          (const __attribute__((address_space(1))) void*)(bgp[i] + kc * 64),
          (__attribute__((address_space(3))) void*)(&ldsB[buf][(i * 4 + wid) * 512]), 16, 0, 0);
  };

  f32x4 acc[4][NF] = {};
  stage(0, 0);
  __syncthreads();
  for (int kc = 0; kc < NK; kc++) {
    if (kc + 1 < NK) stage(kc + 1, (kc + 1) & 1);
    const u16* bufA = ldsA[kc & 1];
    const u16* bufB = ldsB[kc & 1];
#pragma unroll
    for (int kt = 0; kt < 2; kt++) {
      bf16x8 a[4], b[NF];
#pragma unroll
      for (int mi = 0; mi < 4; mi++)
        a[mi] = *reinterpret_cast<const bf16x8*>(&bufA[(wm * 64 + mi * 16 + lo) * 64 + kt * 32 + hi * 8]);
#pragma unroll
      for (int nj = 0; nj < NF; nj++)
        b[nj] = *reinterpret_cast<const bf16x8*>(&bufB[(wn * (BN / 2) + nj * 16 + lo) * 64 + kt * 32 + hi * 8]);
#pragma unroll
      for (int mi = 0; mi < 4; mi++)
#pragma unroll
        for (int nj = 0; nj < NF; nj++)
          acc[mi][nj] = __builtin_amdgcn_mfma_f32_16x16x32_bf16(a[mi], b[nj], acc[mi][nj], 0, 0, 0);
    }
    __syncthreads();
  }
#pragma unroll
  for (int mi = 0; mi < 4; mi++)
#pragma unroll
    for (int nj = 0; nj < NF; nj++) {
      int gn = n0 + wn * (BN / 2) + nj * 16 + lo;
      float bv = bias[gn];
#pragma unroll
      for (int r = 0; r < 4; r++) {
        int gm = m0 + wm * 64 + mi * 16 + hi * 4 + r;
        size_t oidx = (size_t)gm * Nout + gn;
        float v = acc[mi][nj][r] + bv;
        if (EP == EP_BF16)           ((u16*)outp)[oidx] = f2b(v);
        else if (EP == EP_GELU_BF16) ((u16*)outp)[oidx] = f2b(gelu_f(v));
        else                         ((float*)outp)[oidx] = gelu_f(v) + b2f(((const u16*)aux)[oidx]);
      }
    }
}

// ---------------- out-proj GEMM + residual + LN2 fused ----------------
// BN=192 (full row in one block) -> per-row LN stats in-block.
__global__ __launch_bounds__(256, 2) void k_oproj_ln(const u16* __restrict__ A,
                                                     const u16* __restrict__ W,
                                                     const float* __restrict__ bias,
                                                     const u16* __restrict__ resid,
                                                     const float* __restrict__ g,
                                                     const float* __restrict__ bt,
                                                     u16* __restrict__ xp2,
                                                     u16* __restrict__ xn) {
  __shared__ __align__(16) u16 ldsA[2][128 * 64];
  __shared__ __align__(16) u16 ldsB[2][192 * 64];
  const int tid = threadIdx.x;
  const int lane = tid & 63, wid = tid >> 6;
  const int lo = lane & 15, hi = lane >> 4;
  const int wm = wid >> 1, wn = wid & 1;
  const size_t m0 = (size_t)blockIdx.x * 128;
  const int lrow = lane >> 3, lk = (lane & 7) * 8;

  auto stage = [&](int kc, int buf) {
#pragma unroll
    for (int i = 0; i < 4; i++)
      __builtin_amdgcn_global_load_lds(
          (const __attribute__((address_space(1))) void*)(A + (m0 + i * 32 + wid * 8 + lrow) * 192 + kc * 64 + lk),
          (__attribute__((address_space(3))) void*)(&ldsA[buf][(i * 4 + wid) * 512]), 16, 0, 0);
#pragma unroll
    for (int i = 0; i < 6; i++)
      __builtin_amdgcn_global_load_lds(
          (const __attribute__((address_space(1))) void*)(W + (size_t)(i * 32 + wid * 8 + lrow) * 192 + kc * 64 + lk),
          (__attribute__((address_space(3))) void*)(&ldsB[buf][(i * 4 + wid) * 512]), 16, 0, 0);
  };

  f32x4 acc[4][6] = {};
  stage(0, 0);
  __syncthreads();
  for (int kc = 0; kc < 3; kc++) {
    if (kc + 1 < 3) stage(kc + 1, (kc + 1) & 1);
    const u16* bufA = ldsA[kc & 1];
    const u16* bufB = ldsB[kc & 1];
#pragma unroll
    for (int kt = 0; kt < 2; kt++) {
      bf16x8 a[4], b[6];
#pragma unroll
      for (int mi = 0; mi < 4; mi++)
        a[mi] = *reinterpret_cast<const bf16x8*>(&bufA[(wm * 64 + mi * 16 + lo) * 64 + kt * 32 + hi * 8]);
#pragma unroll
      for (int nj = 0; nj < 6; nj++)
        b[nj] = *reinterpret_cast<const bf16x8*>(&bufB[(wn * 96 + nj * 16 + lo) * 64 + kt * 32 + hi * 8]);
#pragma unroll
      for (int mi = 0; mi < 4; mi++)
#pragma unroll
        for (int nj = 0; nj < 6; nj++)
          acc[mi][nj] = __builtin_amdgcn_mfma_f32_16x16x32_bf16(a[mi], b[nj], acc[mi][nj], 0, 0, 0);
    }
    __syncthreads();
  }
  // v = acc + bias + resid (in place)
  float bv[6];
#pragma unroll
  for (int nj = 0; nj < 6; nj++) bv[nj] = bias[wn * 96 + nj * 16 + lo];
#pragma unroll
  for (int mi = 0; mi < 4; mi++)
#pragma unroll
    for (int r = 0; r < 4; r++) {
      size_t gm = m0 + wm * 64 + mi * 16 + hi * 4 + r;
#pragma unroll
      for (int nj = 0; nj < 6; nj++)
        acc[mi][nj][r] += bv[nj] + b2f(resid[gm * 192 + wn * 96 + nj * 16 + lo]);
    }
  // per-row stats: reduce 16 lo-lanes, then across 2 wn-waves via LDS
  float* scr_s = (float*)&ldsA[0][0];   // 256 floats
  float* scr_q = scr_s + 256;
#pragma unroll
  for (int mi = 0; mi < 4; mi++)
#pragma unroll
    for (int r = 0; r < 4; r++) {
      float s = 0.f, q = 0.f;
#pragma unroll
      for (int nj = 0; nj < 6; nj++) { float v = acc[mi][nj][r]; s += v; q += v * v; }
      s += __shfl_xor(s, 1, 64); q += __shfl_xor(q, 1, 64);
      s += __shfl_xor(s, 2, 64); q += __shfl_xor(q, 2, 64);
      s += __shfl_xor(s, 4, 64); q += __shfl_xor(q, 4, 64);
      s += __shfl_xor(s, 8, 64); q += __shfl_xor(q, 8, 64);
      if (lo == 0) {
        int row = wm * 64 + mi * 16 + hi * 4 + r;
        scr_s[row * 2 + wn] = s;
        scr_q[row * 2 + wn] = q;
      }
    }
  __syncthreads();
#pragma unroll
  for (int mi = 0; mi < 4; mi++)
#pragma unroll
    for (int r = 0; r < 4; r++) {
      int row = wm * 64 + mi * 16 + hi * 4 + r;
      float s = scr_s[row * 2] + scr_s[row * 2 + 1];
      float q = scr_q[row * 2] + scr_q[row * 2 + 1];
      float mean = s * (1.f / 192.f);
      float rstd = rsqrtf(q * (1.f / 192.f) - mean * mean + 1e-5f);
#pragma unroll
      for (int nj = 0; nj < 6; nj++) {
        int gn = wn * 96 + nj * 16 + lo;
        size_t oidx = (m0 + row) * 192 + gn;
        float v = acc[mi][nj][r];
        xp2[oidx] = f2b(v);
        xn[oidx] = f2b((v - mean) * rstd * g[gn] + bt[gn]);
      }
    }
}

// ---------------- windowed attention v2: direct Q/K loads, 2 blocks/CU ----------------
__global__ __launch_bounds__(384, 3) void k_attn2(const u16* __restrict__ qkv, u16* __restrict__ o) {
  __shared__ __align__(16) u16 vt[192 * 72];       // V^T [d][token]
  __shared__ __align__(16) u16 pbuf[6 * 64 * 64];  // per-head P, XOR-swizzled rows
  const int tid = threadIdx.x;
  const int wid = tid >> 6, lane = tid & 63, lo = lane & 15, hi = lane >> 4;
  const u16* src = qkv + (size_t)blockIdx.x * 64 * 576;
  // V transpose stage
  for (int i = 0; i < 4; i++) {
    int gq = i * 384 + tid, row = gq / 24, kk = gq - row * 24;
    uint4 d = *reinterpret_cast<const uint4*>(src + row * 576 + 384 + kk * 8);
    const u16* ds = (const u16*)&d;
#pragma unroll
    for (int e = 0; e < 8; e++) vt[(kk * 8 + e) * 72 + row] = ds[e];
  }
  // QK^T: direct global loads (each element read by exactly one wave)
  bf16x8 qa[4], kb[4];
#pragma unroll
  for (int mi = 0; mi < 4; mi++)
    qa[mi] = *reinterpret_cast<const bf16x8*>(src + (size_t)(mi * 16 + lo) * 576 + wid * 32 + hi * 8);
#pragma unroll
  for (int nj = 0; nj < 4; nj++)
    kb[nj] = *reinterpret_cast<const bf16x8*>(src + (size_t)(nj * 16 + lo) * 576 + 192 + wid * 32 + hi * 8);
  f32x4 s[4][4] = {};
#pragma unroll
  for (int mi = 0; mi < 4; mi++)
#pragma unroll
    for (int nj = 0; nj < 4; nj++)
      s[mi][nj] = __builtin_amdgcn_mfma_f32_16x16x32_bf16(qa[mi], kb[nj], s[mi][nj], 0, 0, 0);
  const float scale = 0.1767766952966369f;
#pragma unroll
  for (int mi = 0; mi < 4; mi++)
#pragma unroll
    for (int nj = 0; nj < 4; nj++)
#pragma unroll
      for (int r = 0; r < 4; r++) s[mi][nj][r] *= scale;
  // softmax per row + swizzled P write
  const int l3 = lo & 7, lh = lo >> 3;
#pragma unroll
  for (int mi = 0; mi < 4; mi++)
#pragma unroll
    for (int r = 0; r < 4; r++) {
      float mx = fmaxf(fmaxf(s[mi][0][r], s[mi][1][r]), fmaxf(s[mi][2][r], s[mi][3][r]));
      mx = fmaxf(mx, __shfl_xor(mx, 1, 64));
      mx = fmaxf(mx, __shfl_xor(mx, 2, 64));
      mx = fmaxf(mx, __shfl_xor(mx, 4, 64));
      mx = fmaxf(mx, __shfl_xor(mx, 8, 64));
      float e0 = __expf(s[mi][0][r] - mx), e1 = __expf(s[mi][1][r] - mx);
      float e2 = __expf(s[mi][2][r] - mx), e3 = __expf(s[mi][3][r] - mx);
      float sm = e0 + e1 + e2 + e3;
      sm += __shfl_xor(sm, 1, 64);
      sm += __shfl_xor(sm, 2, 64);
      sm += __shfl_xor(sm, 4, 64);
      sm += __shfl_xor(sm, 8, 64);
      float inv = 1.0f / sm;
      int ii = mi * 16 + hi * 4 + r;
      u16* bse = pbuf + wid * 4096 + ii * 64;
      int x7 = ii & 7;
      bse[((lh)     ^ x7) * 8 + l3] = f2b(e0 * inv);
      bse[((2 + lh) ^ x7) * 8 + l3] = f2b(e1 * inv);
      bse[((4 + lh) ^ x7) * 8 + l3] = f2b(e2 * inv);
      bse[((6 + lh) ^ x7) * 8 + l3] = f2b(e3 * inv);
    }
  __syncthreads();
  // O = P @ V
  f32x4 oacc[4][2] = {};
#pragma unroll
  for (int kt = 0; kt < 2; kt++) {
    bf16x8 pa[4], vb[2];
#pragma unroll
    for (int mi = 0; mi < 4; mi++) {
      int row = mi * 16 + lo;
      pa[mi] = *reinterpret_cast<const bf16x8*>(pbuf + wid * 4096 + row * 64 + ((kt * 4 + hi) ^ (row & 7)) * 8);
    }
#pragma unroll
    for (int ni = 0; ni < 2; ni++)
      vb[ni] = *reinterpret_cast<const bf16x8*>(vt + (wid * 32 + ni * 16 + lo) * 72 + kt * 32 + hi * 8);
#pragma unroll
    for (int mi = 0; mi < 4; mi++)
#pragma unroll
      for (int ni = 0; ni < 2; ni++)
        oacc[mi][ni] = __builtin_amdgcn_mfma_f32_16x16x32_bf16(pa[mi], vb[ni], oacc[mi][ni], 0, 0, 0);
  }
#pragma unroll
  for (int mi = 0; mi < 4; mi++)
#pragma unroll
    for (int ni = 0; ni < 2; ni++)
#pragma unroll
      for (int r = 0; r < 4; r++) {
        int i = mi * 16 + hi * 4 + r, d = ni * 16 + lo;
        o[((size_t)blockIdx.x * 64 + i) * 192 + wid * 32 + d] = f2b(oacc[mi][ni][r]);
      }
}

// ---------------- un-patchify ----------------
__global__ __launch_bounds__(256) void k_unpatch(const float* __restrict__ xf, float* __restrict__ outp, int b0) {
  __shared__ float tile[128 * 65];
  const int cc = blockIdx.x, h = blockIdx.y, bb = blockIdx.z, b = b0 + bb;
  const int tid = threadIdx.x;
  const int p1 = h & 7, hy = h >> 3;
  for (int i = 0; i < 32; i++) {
    int idx = i * 256 + tid, t = idx >> 6, c = idx & 63;
    int wx = t >> 3, p2 = t & 7;
    int rr = ((bb * 16 + hy) * 16 + wx) * 64 + p1 * 8 + p2;
    tile[t * 65 + c] = xf[(size_t)rr * 192 + cc * 64 + c];
  }
  __syncthreads();
  for (int i = 0; i < 32; i++) {
    int idx = i * 256 + tid, c = idx >> 7, w = idx & 127;
    outp[((size_t)(b * 192 + cc * 64 + c) * 128 + h) * 128 + w] = tile[w * 65 + c];
  }
}

extern "C" void kernel_launch(void* const* d_in, const int* in_sizes, int n_in,
                              void* d_out, int out_size, void* d_ws, size_t ws_size,
                              hipStream_t stream) {
  const float* x    = (const float*)d_in[0];
  const float* rowe = (const float*)d_in[1];
  const float* cole = (const float*)d_in[2];
  const float* ln1g = (const float*)d_in[3];
  const float* ln1b = (const float*)d_in[4];
  const float* ipw  = (const float*)d_in[5];
  const float* ipb  = (const float*)d_in[6];
  const float* outw = (const float*)d_in[7];
  const float* outb = (const float*)d_in[8];
  const float* ln2g = (const float*)d_in[9];
  const float* ln2b = (const float*)d_in[10];
  const float* w1   = (const float*)d_in[11];
  const float* b1   = (const float*)d_in[12];
  const float* w2   = (const float*)d_in[13];
  const float* b2   = (const float*)d_in[14];
  float* outp = (float*)d_out;

  char* p = (char*)d_ws;
  auto alloc = [&](size_t bytes) -> void* {
    void* r = (void*)p;
    p += (bytes + 255) & ~(size_t)255;
    return r;
  };
  u16* wq  = (u16*)alloc(110592 * 2);
  u16* wo  = (u16*)alloc(36864 * 2);
  u16* wf1 = (u16*)alloc(147456 * 2);
  u16* wf2 = (u16*)alloc(147456 * 2);

  size_t used = (size_t)(p - (char*)d_ws);
  size_t avail = (ws_size > used) ? (ws_size - used) : 0;
  // per-token bytes: resid 384 + xn 384 + big 1536 + obuf 384 + xp2 384 + xfin 768 = 3840
  int NC = 1;
  while (NC < 8 && (size_t)(131072 / NC) * 3840 + 8192 > avail) NC *= 2;
  const int Bc = 8 / NC;
  const size_t Mc = (size_t)Bc * 16384;

  u16*   resid = (u16*)alloc(Mc * 192 * 2);
  u16*   xn    = (u16*)alloc(Mc * 192 * 2);
  u16*   big   = (u16*)alloc(Mc * 768 * 2);  // qkv then h1
  u16*   obuf  = (u16*)alloc(Mc * 192 * 2);
  u16*   xp2   = (u16*)alloc(Mc * 192 * 2);
  float* xfin  = (float*)alloc(Mc * 192 * 4);

  k_cvt<<<dim3((110592 + 255) / 256), dim3(256), 0, stream>>>(ipw, wq, 110592);
  k_cvt<<<dim3((36864 + 255) / 256), dim3(256), 0, stream>>>(outw, wo, 36864);
  k_cvt<<<dim3((147456 + 255) / 256), dim3(256), 0, stream>>>(w1, wf1, 147456);
  k_cvt<<<dim3((147456 + 255) / 256), dim3(256), 0, stream>>>(w2, wf2, 147456);

  for (int ch = 0; ch < NC; ch++) {
    int b0 = ch * Bc;
    k_patchify_ln<<<dim3(128, Bc), dim3(256), 0, stream>>>(x, rowe, cole, ln1g, ln1b, resid, xn, b0);
    k_gemm3<96, EP_BF16, 192><<<dim3(6, (unsigned)(Mc / 128)), dim3(256), 0, stream>>>(xn, wq, ipb, nullptr, big, 576);
    k_attn2<<<dim3((unsigned)(Bc * 256)), dim3(384), 0, stream>>>(big, obuf);
    k_oproj_ln<<<dim3((unsigned)(Mc / 128)), dim3(256), 0, stream>>>(obuf, wo, outb, resid, ln2g, ln2b, xp2, xn);
    k_gemm3<128, EP_GELU_BF16, 192><<<dim3(6, (unsigned)(Mc / 128)), dim3(256), 0, stream>>>(xn, wf1, b1, nullptr, big, 768);
    k_gemm3<96, EP_GELU_ADD, 768><<<dim3(2, (unsigned)(Mc / 128)), dim3(256), 0, stream>>>(big, wf2, b2, xp2, xfin, 192);
    k_unpatch<<<dim3(3, 128, Bc), dim3(256), 0, stream>>>(xfin, outp, b0);
  }
}

// Round 10
// 660.395 us; speedup vs baseline: 1.6272x; 1.0690x over previous
//
#include <hip/hip_runtime.h>
#include <hip/hip_bf16.h>

typedef unsigned short u16;
typedef __bf16 bf16x8 __attribute__((ext_vector_type(8)));
typedef float f32x4 __attribute__((ext_vector_type(4)));

__device__ __forceinline__ u16 f2b(float f) {
  __hip_bfloat16 h = __float2bfloat16(f);
  return *reinterpret_cast<u16*>(&h);
}
__device__ __forceinline__ float b2f(u16 v) {
  unsigned int u = ((unsigned int)v) << 16;
  union { unsigned int u; float f; } c; c.u = u; return c.f;
}
// tanh-approx GELU via exp2: max |err| ~3e-4
__device__ __forceinline__ float gelu_f(float x) {
  float t = x * x;
  float u = x * fmaf(t, -0.10294576f, -2.30220813f);
  float e = exp2f(u);
  return x * __builtin_amdgcn_rcpf(1.0f + e);
}

// ---------------- weight f32 -> bf16 ----------------
__global__ __launch_bounds__(256) void k_cvt(const float* __restrict__ s, u16* __restrict__ d, int n) {
  int i = blockIdx.x * 256 + threadIdx.x;
  if (i < n) d[i] = f2b(s[i]);
}

// ---------------- patchify + pos-embed + LN1 fused ----------------
__global__ __launch_bounds__(256) void k_patchify_ln(const float* __restrict__ x,
                                                     const float* __restrict__ rowe,
                                                     const float* __restrict__ cole,
                                                     const float* __restrict__ g,
                                                     const float* __restrict__ bta,
                                                     u16* __restrict__ resid,
                                                     u16* __restrict__ xn, int b0) {
  __shared__ float tile[192 * 133];
  __shared__ float ps[256], pq[256], mb[128], rb[128];
  const int h = blockIdx.x, bb = blockIdx.y, b = b0 + bb;
  const int tid = threadIdx.x;
  const int p1 = h & 7, hy = h >> 3;
  const float* xs = x + ((size_t)b * 192 * 128 + (size_t)h) * 128;
  for (int i = 0; i < 24; i++) {
    int idx = i * 256 + tid;
    int c = idx >> 5, w4 = idx & 31;
    const float4 v = *reinterpret_cast<const float4*>(xs + (size_t)c * 16384 + w4 * 4);
    float a0, a1, a2, a3;
    if (c < 96) {
      float pv = rowe[p1 * 96 + c];
      a0 = a1 = a2 = a3 = pv;
    } else {
      int w = w4 * 4;
      a0 = cole[((w)     & 7) * 96 + c - 96];
      a1 = cole[((w + 1) & 7) * 96 + c - 96];
      a2 = cole[((w + 2) & 7) * 96 + c - 96];
      a3 = cole[((w + 3) & 7) * 96 + c - 96];
    }
    float* t = &tile[c * 133 + w4 * 4];
    t[0] = v.x + a0; t[1] = v.y + a1; t[2] = v.z + a2; t[3] = v.w + a3;
  }
  __syncthreads();
  {
    int w = tid & 127, half = tid >> 7;
    float s = 0.f, q = 0.f;
    for (int c = half * 96; c < half * 96 + 96; c++) {
      float v = tile[c * 133 + w];
      s += v; q += v * v;
    }
    ps[tid] = s; pq[tid] = q;
  }
  __syncthreads();
  if (tid < 128) {
    float s = ps[tid] + ps[tid + 128];
    float q = pq[tid] + pq[tid + 128];
    float mean = s * (1.f / 192.f);
    float var = q * (1.f / 192.f) - mean * mean;
    mb[tid] = mean;
    rb[tid] = rsqrtf(var + 1e-5f);
  }
  __syncthreads();
  for (int i = 0; i < 96; i++) {
    int idx = i * 256 + tid;
    int w = idx / 192, c = idx - w * 192;
    float v = tile[c * 133 + w];
    int wx = w >> 3, p2 = w & 7;
    size_t rr = ((size_t)((bb * 16 + hy) * 16 + wx)) * 64 + p1 * 8 + p2;
    resid[rr * 192 + c] = f2b(v);
    xn[rr * 192 + c] = f2b((v - mb[w]) * rb[w] * g[c] + bta[c]);
  }
}

// ---------------- 2-deep pipelined GEMM (R5 structure) ----------------
enum { EP_BF16 = 0, EP_GELU_BF16 = 1 };

template <int BN, int EP, int KTOT>
__global__ __launch_bounds__(256, 2) void k_gemm3(const u16* __restrict__ A,
                                                  const u16* __restrict__ W,
                                                  const float* __restrict__ bias,
                                                  void* __restrict__ outp, int Nout) {
  constexpr int NF = BN / 32;
  constexpr int NBS = BN / 32;
  constexpr int NK = KTOT / 64;
  __shared__ __align__(16) u16 ldsA[2][128 * 64];
  __shared__ __align__(16) u16 ldsB[2][BN * 64];
  const int tid = threadIdx.x;
  const int lane = tid & 63, wid = tid >> 6;
  const int lo = lane & 15, hi = lane >> 4;
  const int wm = wid >> 1, wn = wid & 1;
  const int n0 = blockIdx.x * BN;
  const int m0 = blockIdx.y * 128;

  const int lrow = lane >> 3, lk = (lane & 7) * 8;
  const u16* agp[4];
  const u16* bgp[NBS];
#pragma unroll
  for (int i = 0; i < 4; i++)
    agp[i] = A + (size_t)(m0 + i * 32 + wid * 8 + lrow) * KTOT + lk;
#pragma unroll
  for (int i = 0; i < NBS; i++)
    bgp[i] = W + (size_t)(n0 + i * 32 + wid * 8 + lrow) * KTOT + lk;

  auto stage = [&](int kc, int buf) {
#pragma unroll
    for (int i = 0; i < 4; i++)
      __builtin_amdgcn_global_load_lds(
          (const __attribute__((address_space(1))) void*)(agp[i] + kc * 64),
          (__attribute__((address_space(3))) void*)(&ldsA[buf][(i * 4 + wid) * 512]), 16, 0, 0);
#pragma unroll
    for (int i = 0; i < NBS; i++)
      __builtin_amdgcn_global_load_lds(
          (const __attribute__((address_space(1))) void*)(bgp[i] + kc * 64),
          (__attribute__((address_space(3))) void*)(&ldsB[buf][(i * 4 + wid) * 512]), 16, 0, 0);
  };

  f32x4 acc[4][NF] = {};
  stage(0, 0);
  __syncthreads();
  for (int kc = 0; kc < NK; kc++) {
    if (kc + 1 < NK) stage(kc + 1, (kc + 1) & 1);
    const u16* bufA = ldsA[kc & 1];
    const u16* bufB = ldsB[kc & 1];
#pragma unroll
    for (int kt = 0; kt < 2; kt++) {
      bf16x8 a[4], b[NF];
#pragma unroll
      for (int mi = 0; mi < 4; mi++)
        a[mi] = *reinterpret_cast<const bf16x8*>(&bufA[(wm * 64 + mi * 16 + lo) * 64 + kt * 32 + hi * 8]);
#pragma unroll
      for (int nj = 0; nj < NF; nj++)
        b[nj] = *reinterpret_cast<const bf16x8*>(&bufB[(wn * (BN / 2) + nj * 16 + lo) * 64 + kt * 32 + hi * 8]);
#pragma unroll
      for (int mi = 0; mi < 4; mi++)
#pragma unroll
        for (int nj = 0; nj < NF; nj++)
          acc[mi][nj] = __builtin_amdgcn_mfma_f32_16x16x32_bf16(a[mi], b[nj], acc[mi][nj], 0, 0, 0);
    }
    __syncthreads();
  }
#pragma unroll
  for (int mi = 0; mi < 4; mi++)
#pragma unroll
    for (int nj = 0; nj < NF; nj++) {
      int gn = n0 + wn * (BN / 2) + nj * 16 + lo;
      float bv = bias[gn];
#pragma unroll
      for (int r = 0; r < 4; r++) {
        int gm = m0 + wm * 64 + mi * 16 + hi * 4 + r;
        size_t oidx = (size_t)gm * Nout + gn;
        float v = acc[mi][nj][r] + bv;
        if (EP == EP_BF16) ((u16*)outp)[oidx] = f2b(v);
        else               ((u16*)outp)[oidx] = f2b(gelu_f(v));
      }
    }
}

// ---------------- FFN2 + gelu + residual-add + un-patchify fused ----------------
// BN=96, K=768. Epilogue: f32 transpose tile [c][px] (aliased on staging LDS),
// then 64B-line stores direct to out(B,C,H,W): block = 2 adjacent windows.
__global__ __launch_bounds__(256, 2) void k_ffn2_up(const u16* __restrict__ A,
                                                    const u16* __restrict__ W,
                                                    const float* __restrict__ bias,
                                                    const u16* __restrict__ xp2,
                                                    float* __restrict__ outp, int b0) {
  __shared__ __align__(16) u16 smem[2 * 128 * 64 + 2 * 96 * 64];  // 56 KB
  u16* ldsA = smem;                  // [2][128*64]
  u16* ldsB = smem + 2 * 128 * 64;   // [2][96*64]
  float* trans = (float*)smem;       // [96][129] f32 = 49.5 KB (aliased after K-loop)
  const int tid = threadIdx.x;
  const int lane = tid & 63, wid = tid >> 6;
  const int lo = lane & 15, hi = lane >> 4;
  const int wm = wid >> 1, wn = wid & 1;
  const int n0 = blockIdx.x * 96;
  const size_t m0 = (size_t)blockIdx.y * 128;
  const int lrow = lane >> 3, lk = (lane & 7) * 8;

  auto stage = [&](int kc, int buf) {
#pragma unroll
    for (int i = 0; i < 4; i++)
      __builtin_amdgcn_global_load_lds(
          (const __attribute__((address_space(1))) void*)(A + (m0 + i * 32 + wid * 8 + lrow) * 768 + kc * 64 + lk),
          (__attribute__((address_space(3))) void*)(ldsA + buf * 8192 + (i * 4 + wid) * 512), 16, 0, 0);
#pragma unroll
    for (int i = 0; i < 3; i++)
      __builtin_amdgcn_global_load_lds(
          (const __attribute__((address_space(1))) void*)(W + (size_t)(n0 + i * 32 + wid * 8 + lrow) * 768 + kc * 64 + lk),
          (__attribute__((address_space(3))) void*)(ldsB + buf * 6144 + (i * 4 + wid) * 512), 16, 0, 0);
  };

  f32x4 acc[4][3] = {};
  stage(0, 0);
  __syncthreads();
  for (int kc = 0; kc < 12; kc++) {
    if (kc + 1 < 12) stage(kc + 1, (kc + 1) & 1);
    const u16* bufA = ldsA + (kc & 1) * 8192;
    const u16* bufB = ldsB + (kc & 1) * 6144;
#pragma unroll
    for (int kt = 0; kt < 2; kt++) {
      bf16x8 a[4], b[3];
#pragma unroll
      for (int mi = 0; mi < 4; mi++)
        a[mi] = *reinterpret_cast<const bf16x8*>(&bufA[(wm * 64 + mi * 16 + lo) * 64 + kt * 32 + hi * 8]);
#pragma unroll
      for (int nj = 0; nj < 3; nj++)
        b[nj] = *reinterpret_cast<const bf16x8*>(&bufB[(wn * 48 + nj * 16 + lo) * 64 + kt * 32 + hi * 8]);
#pragma unroll
      for (int mi = 0; mi < 4; mi++)
#pragma unroll
        for (int nj = 0; nj < 3; nj++)
          acc[mi][nj] = __builtin_amdgcn_mfma_f32_16x16x32_bf16(a[mi], b[nj], acc[mi][nj], 0, 0, 0);
    }
    __syncthreads();
  }
  // epilogue part 1: v = gelu(acc+bias) + xp2; write f32 transpose tile [cl][px]
  float bv[3];
#pragma unroll
  for (int nj = 0; nj < 3; nj++) bv[nj] = bias[n0 + wn * 48 + nj * 16 + lo];
#pragma unroll
  for (int mi = 0; mi < 4; mi++)
#pragma unroll
    for (int nj = 0; nj < 3; nj++) {
      int cl = wn * 48 + nj * 16 + lo;
#pragma unroll
      for (int r = 0; r < 4; r++) {
        int px = wm * 64 + mi * 16 + hi * 4 + r;
        float v = gelu_f(acc[mi][nj][r] + bv[nj]) + b2f(xp2[(m0 + px) * 192 + n0 + cl]);
        trans[cl * 129 + px] = v;
      }
    }
  __syncthreads();
  // epilogue part 2: store to out(B,192,128,128). 96*128/256 = 48 f32 = 12 float4/thread.
  // block tokens = windows (wnd0, wnd0+1), wnd0 even -> same (b,hy), wx & wx+1 -> 16-consec w.
#pragma unroll
  for (int j = 0; j < 12; j++) {
    int q = j * 256 + tid;          // 0..3071
    int c = q >> 5;                 // 0..95
    int wq = q & 31;
    int px = wq * 4;
    float v0 = trans[c * 129 + px];
    float v1 = trans[c * 129 + px + 1];
    float v2 = trans[c * 129 + px + 2];
    float v3 = trans[c * 129 + px + 3];
    int tok = (int)m0 + px;
    int wnd = tok >> 6, p = tok & 63;
    int p1 = p >> 3, p2 = p & 7;
    int bb = wnd >> 8, hy = (wnd >> 4) & 15, wx = wnd & 15;
    size_t o = (((size_t)((b0 + bb) * 192 + n0 + c) * 128) + hy * 8 + p1) * 128 + wx * 8 + p2;
    float4 v = make_float4(v0, v1, v2, v3);
    *reinterpret_cast<float4*>(outp + o) = v;
  }
}

// ---------------- out-proj GEMM + residual + LN2 fused ----------------
__global__ __launch_bounds__(256, 2) void k_oproj_ln(const u16* __restrict__ A,
                                                     const u16* __restrict__ W,
                                                     const float* __restrict__ bias,
                                                     const u16* __restrict__ resid,
                                                     const float* __restrict__ g,
                                                     const float* __restrict__ bt,
                                                     u16* __restrict__ xp2,
                                                     u16* __restrict__ xn) {
  __shared__ __align__(16) u16 ldsA[2][128 * 64];
  __shared__ __align__(16) u16 ldsB[2][192 * 64];
  const int tid = threadIdx.x;
  const int lane = tid & 63, wid = tid >> 6;
  const int lo = lane & 15, hi = lane >> 4;
  const int wm = wid >> 1, wn = wid & 1;
  const size_t m0 = (size_t)blockIdx.x * 128;
  const int lrow = lane >> 3, lk = (lane & 7) * 8;

  auto stage = [&](int kc, int buf) {
#pragma unroll
    for (int i = 0; i < 4; i++)
      __builtin_amdgcn_global_load_lds(
          (const __attribute__((address_space(1))) void*)(A + (m0 + i * 32 + wid * 8 + lrow) * 192 + kc * 64 + lk),
          (__attribute__((address_space(3))) void*)(&ldsA[buf][(i * 4 + wid) * 512]), 16, 0, 0);
#pragma unroll
    for (int i = 0; i < 6; i++)
      __builtin_amdgcn_global_load_lds(
          (const __attribute__((address_space(1))) void*)(W + (size_t)(i * 32 + wid * 8 + lrow) * 192 + kc * 64 + lk),
          (__attribute__((address_space(3))) void*)(&ldsB[buf][(i * 4 + wid) * 512]), 16, 0, 0);
  };

  f32x4 acc[4][6] = {};
  stage(0, 0);
  __syncthreads();
  for (int kc = 0; kc < 3; kc++) {
    if (kc + 1 < 3) stage(kc + 1, (kc + 1) & 1);
    const u16* bufA = ldsA[kc & 1];
    const u16* bufB = ldsB[kc & 1];
#pragma unroll
    for (int kt = 0; kt < 2; kt++) {
      bf16x8 a[4], b[6];
#pragma unroll
      for (int mi = 0; mi < 4; mi++)
        a[mi] = *reinterpret_cast<const bf16x8*>(&bufA[(wm * 64 + mi * 16 + lo) * 64 + kt * 32 + hi * 8]);
#pragma unroll
      for (int nj = 0; nj < 6; nj++)
        b[nj] = *reinterpret_cast<const bf16x8*>(&bufB[(wn * 96 + nj * 16 + lo) * 64 + kt * 32 + hi * 8]);
#pragma unroll
      for (int mi = 0; mi < 4; mi++)
#pragma unroll
        for (int nj = 0; nj < 6; nj++)
          acc[mi][nj] = __builtin_amdgcn_mfma_f32_16x16x32_bf16(a[mi], b[nj], acc[mi][nj], 0, 0, 0);
    }
    __syncthreads();
  }
  float bv[6];
#pragma unroll
  for (int nj = 0; nj < 6; nj++) bv[nj] = bias[wn * 96 + nj * 16 + lo];
#pragma unroll
  for (int mi = 0; mi < 4; mi++)
#pragma unroll
    for (int r = 0; r < 4; r++) {
      size_t gm = m0 + wm * 64 + mi * 16 + hi * 4 + r;
#pragma unroll
      for (int nj = 0; nj < 6; nj++)
        acc[mi][nj][r] += bv[nj] + b2f(resid[gm * 192 + wn * 96 + nj * 16 + lo]);
    }
  float* scr_s = (float*)&ldsA[0][0];
  float* scr_q = scr_s + 256;
#pragma unroll
  for (int mi = 0; mi < 4; mi++)
#pragma unroll
    for (int r = 0; r < 4; r++) {
      float s = 0.f, q = 0.f;
#pragma unroll
      for (int nj = 0; nj < 6; nj++) { float v = acc[mi][nj][r]; s += v; q += v * v; }
      s += __shfl_xor(s, 1, 64); q += __shfl_xor(q, 1, 64);
      s += __shfl_xor(s, 2, 64); q += __shfl_xor(q, 2, 64);
      s += __shfl_xor(s, 4, 64); q += __shfl_xor(q, 4, 64);
      s += __shfl_xor(s, 8, 64); q += __shfl_xor(q, 8, 64);
      if (lo == 0) {
        int row = wm * 64 + mi * 16 + hi * 4 + r;
        scr_s[row * 2 + wn] = s;
        scr_q[row * 2 + wn] = q;
      }
    }
  __syncthreads();
#pragma unroll
  for (int mi = 0; mi < 4; mi++)
#pragma unroll
    for (int r = 0; r < 4; r++) {
      int row = wm * 64 + mi * 16 + hi * 4 + r;
      float s = scr_s[row * 2] + scr_s[row * 2 + 1];
      float q = scr_q[row * 2] + scr_q[row * 2 + 1];
      float mean = s * (1.f / 192.f);
      float rstd = rsqrtf(q * (1.f / 192.f) - mean * mean + 1e-5f);
#pragma unroll
      for (int nj = 0; nj < 6; nj++) {
        int gn = wn * 96 + nj * 16 + lo;
        size_t oidx = (m0 + row) * 192 + gn;
        float v = acc[mi][nj][r];
        xp2[oidx] = f2b(v);
        xn[oidx] = f2b((v - mean) * rstd * g[gn] + bt[gn]);
      }
    }
}

// ---------------- windowed attention v2: direct Q/K loads ----------------
__global__ __launch_bounds__(384, 3) void k_attn2(const u16* __restrict__ qkv, u16* __restrict__ o) {
  __shared__ __align__(16) u16 vt[192 * 72];
  __shared__ __align__(16) u16 pbuf[6 * 64 * 64];
  const int tid = threadIdx.x;
  const int wid = tid >> 6, lane = tid & 63, lo = lane & 15, hi = lane >> 4;
  const u16* src = qkv + (size_t)blockIdx.x * 64 * 576;
  for (int i = 0; i < 4; i++) {
    int gq = i * 384 + tid, row = gq / 24, kk = gq - row * 24;
    uint4 d = *reinterpret_cast<const uint4*>(src + row * 576 + 384 + kk * 8);
    const u16* ds = (const u16*)&d;
#pragma unroll
    for (int e = 0; e < 8; e++) vt[(kk * 8 + e) * 72 + row] = ds[e];
  }
  bf16x8 qa[4], kb[4];
#pragma unroll
  for (int mi = 0; mi < 4; mi++)
    qa[mi] = *reinterpret_cast<const bf16x8*>(src + (size_t)(mi * 16 + lo) * 576 + wid * 32 + hi * 8);
#pragma unroll
  for (int nj = 0; nj < 4; nj++)
    kb[nj] = *reinterpret_cast<const bf16x8*>(src + (size_t)(nj * 16 + lo) * 576 + 192 + wid * 32 + hi * 8);
  f32x4 s[4][4] = {};
#pragma unroll
  for (int mi = 0; mi < 4; mi++)
#pragma unroll
    for (int nj = 0; nj < 4; nj++)
      s[mi][nj] = __builtin_amdgcn_mfma_f32_16x16x32_bf16(qa[mi], kb[nj], s[mi][nj], 0, 0, 0);
  const float scale = 0.1767766952966369f;
#pragma unroll
  for (int mi = 0; mi < 4; mi++)
#pragma unroll
    for (int nj = 0; nj < 4; nj++)
#pragma unroll
      for (int r = 0; r < 4; r++) s[mi][nj][r] *= scale;
  const int l3 = lo & 7, lh = lo >> 3;
#pragma unroll
  for (int mi = 0; mi < 4; mi++)
#pragma unroll
    for (int r = 0; r < 4; r++) {
      float mx = fmaxf(fmaxf(s[mi][0][r], s[mi][1][r]), fmaxf(s[mi][2][r], s[mi][3][r]));
      mx = fmaxf(mx, __shfl_xor(mx, 1, 64));
      mx = fmaxf(mx, __shfl_xor(mx, 2, 64));
      mx = fmaxf(mx, __shfl_xor(mx, 4, 64));
      mx = fmaxf(mx, __shfl_xor(mx, 8, 64));
      float e0 = __expf(s[mi][0][r] - mx), e1 = __expf(s[mi][1][r] - mx);
      float e2 = __expf(s[mi][2][r] - mx), e3 = __expf(s[mi][3][r] - mx);
      float sm = e0 + e1 + e2 + e3;
      sm += __shfl_xor(sm, 1, 64);
      sm += __shfl_xor(sm, 2, 64);
      sm += __shfl_xor(sm, 4, 64);
      sm += __shfl_xor(sm, 8, 64);
      float inv = 1.0f / sm;
      int ii = mi * 16 + hi * 4 + r;
      u16* bse = pbuf + wid * 4096 + ii * 64;
      int x7 = ii & 7;
      bse[((lh)     ^ x7) * 8 + l3] = f2b(e0 * inv);
      bse[((2 + lh) ^ x7) * 8 + l3] = f2b(e1 * inv);
      bse[((4 + lh) ^ x7) * 8 + l3] = f2b(e2 * inv);
      bse[((6 + lh) ^ x7) * 8 + l3] = f2b(e3 * inv);
    }
  __syncthreads();
  f32x4 oacc[4][2] = {};
#pragma unroll
  for (int kt = 0; kt < 2; kt++) {
    bf16x8 pa[4], vb[2];
#pragma unroll
    for (int mi = 0; mi < 4; mi++) {
      int row = mi * 16 + lo;
      pa[mi] = *reinterpret_cast<const bf16x8*>(pbuf + wid * 4096 + row * 64 + ((kt * 4 + hi) ^ (row & 7)) * 8);
    }
#pragma unroll
    for (int ni = 0; ni < 2; ni++)
      vb[ni] = *reinterpret_cast<const bf16x8*>(vt + (wid * 32 + ni * 16 + lo) * 72 + kt * 32 + hi * 8);
#pragma unroll
    for (int mi = 0; mi < 4; mi++)
#pragma unroll
      for (int ni = 0; ni < 2; ni++)
        oacc[mi][ni] = __builtin_amdgcn_mfma_f32_16x16x32_bf16(pa[mi], vb[ni], oacc[mi][ni], 0, 0, 0);
  }
#pragma unroll
  for (int mi = 0; mi < 4; mi++)
#pragma unroll
    for (int ni = 0; ni < 2; ni++)
#pragma unroll
      for (int r = 0; r < 4; r++) {
        int i = mi * 16 + hi * 4 + r, d = ni * 16 + lo;
        o[((size_t)blockIdx.x * 64 + i) * 192 + wid * 32 + d] = f2b(oacc[mi][ni][r]);
      }
}

extern "C" void kernel_launch(void* const* d_in, const int* in_sizes, int n_in,
                              void* d_out, int out_size, void* d_ws, size_t ws_size,
                              hipStream_t stream) {
  const float* x    = (const float*)d_in[0];
  const float* rowe = (const float*)d_in[1];
  const float* cole = (const float*)d_in[2];
  const float* ln1g = (const float*)d_in[3];
  const float* ln1b = (const float*)d_in[4];
  const float* ipw  = (const float*)d_in[5];
  const float* ipb  = (const float*)d_in[6];
  const float* outw = (const float*)d_in[7];
  const float* outb = (const float*)d_in[8];
  const float* ln2g = (const float*)d_in[9];
  const float* ln2b = (const float*)d_in[10];
  const float* w1   = (const float*)d_in[11];
  const float* b1   = (const float*)d_in[12];
  const float* w2   = (const float*)d_in[13];
  const float* b2   = (const float*)d_in[14];
  float* outp = (float*)d_out;

  char* p = (char*)d_ws;
  auto alloc = [&](size_t bytes) -> void* {
    void* r = (void*)p;
    p += (bytes + 255) & ~(size_t)255;
    return r;
  };
  u16* wq  = (u16*)alloc(110592 * 2);
  u16* wo  = (u16*)alloc(36864 * 2);
  u16* wf1 = (u16*)alloc(147456 * 2);
  u16* wf2 = (u16*)alloc(147456 * 2);

  size_t used = (size_t)(p - (char*)d_ws);
  size_t avail = (ws_size > used) ? (ws_size - used) : 0;
  // per-token: resid 384 + xn 384 + big 1536 + obuf 384 + xp2 384 = 3072
  int NC = 1;
  while (NC < 8 && (size_t)(131072 / NC) * 3072 + 8192 > avail) NC *= 2;
  const int Bc = 8 / NC;
  const size_t Mc = (size_t)Bc * 16384;

  u16* resid = (u16*)alloc(Mc * 192 * 2);
  u16* xn    = (u16*)alloc(Mc * 192 * 2);
  u16* big   = (u16*)alloc(Mc * 768 * 2);  // qkv then h1
  u16* obuf  = (u16*)alloc(Mc * 192 * 2);
  u16* xp2   = (u16*)alloc(Mc * 192 * 2);

  k_cvt<<<dim3((110592 + 255) / 256), dim3(256), 0, stream>>>(ipw, wq, 110592);
  k_cvt<<<dim3((36864 + 255) / 256), dim3(256), 0, stream>>>(outw, wo, 36864);
  k_cvt<<<dim3((147456 + 255) / 256), dim3(256), 0, stream>>>(w1, wf1, 147456);
  k_cvt<<<dim3((147456 + 255) / 256), dim3(256), 0, stream>>>(w2, wf2, 147456);

  for (int ch = 0; ch < NC; ch++) {
    int b0 = ch * Bc;
    k_patchify_ln<<<dim3(128, Bc), dim3(256), 0, stream>>>(x, rowe, cole, ln1g, ln1b, resid, xn, b0);
    k_gemm3<96, EP_BF16, 192><<<dim3(6, (unsigned)(Mc / 128)), dim3(256), 0, stream>>>(xn, wq, ipb, big, 576);
    k_attn2<<<dim3((unsigned)(Bc * 256)), dim3(384), 0, stream>>>(big, obuf);
    k_oproj_ln<<<dim3((unsigned)(Mc / 128)), dim3(256), 0, stream>>>(obuf, wo, outb, resid, ln2g, ln2b, xp2, xn);
    k_gemm3<128, EP_GELU_BF16, 192><<<dim3(6, (unsigned)(Mc / 128)), dim3(256), 0, stream>>>(xn, wf1, b1, big, 768);
    k_ffn2_up<<<dim3(2, (unsigned)(Mc / 128)), dim3(256), 0, stream>>>(big, wf2, b2, xp2, outp, b0);
  }
}